// Round 2
// baseline (446.813 us; speedup 1.0000x reference)
//
#include <hip/hip_runtime.h>

// Reference = patchify ∘ depatchify = identity. Pure D2D copy.
// 64*1*1024*1024 floats = 256 MiB in + 256 MiB out = 512 MiB structural floor.
// Copy itself ~90 us (~94% of 6.3 TB/s achievable); reported dur_us also
// contains ~333 us of harness poison-fills (2 x 1 GiB @ ~167 us, per rocprof).
//
// Round 2 = round 1 intent, compile-fixed: __builtin_nontemporal_* requires a
// native clang vector type, not HIP_vector_type<float,4>. Use ext_vector_type.

using f32x4 = __attribute__((ext_vector_type(4))) float;

__global__ __launch_bounds__(256) void copy_f4_nt(const f32x4* __restrict__ src,
                                                  f32x4* __restrict__ dst,
                                                  long long n4) {
    const long long stride = (long long)gridDim.x * blockDim.x;
    long long i = (long long)blockIdx.x * blockDim.x + threadIdx.x;

    // 4-way unrolled grid-stride: 4 independent 16B loads in flight per lane
    // (ILP) on top of 32 waves/CU (TLP).
    for (; i + 3 * stride < n4; i += 4 * stride) {
        f32x4 a = __builtin_nontemporal_load(&src[i]);
        f32x4 b = __builtin_nontemporal_load(&src[i + stride]);
        f32x4 c = __builtin_nontemporal_load(&src[i + 2 * stride]);
        f32x4 d = __builtin_nontemporal_load(&src[i + 3 * stride]);
        __builtin_nontemporal_store(a, &dst[i]);
        __builtin_nontemporal_store(b, &dst[i + stride]);
        __builtin_nontemporal_store(c, &dst[i + 2 * stride]);
        __builtin_nontemporal_store(d, &dst[i + 3 * stride]);
    }
    // Tail (not reached for n4 = 16M with this grid; kept for generality).
    for (; i < n4; i += stride) {
        f32x4 v = __builtin_nontemporal_load(&src[i]);
        __builtin_nontemporal_store(v, &dst[i]);
    }
}

extern "C" void kernel_launch(void* const* d_in, const int* in_sizes, int n_in,
                              void* d_out, int out_size, void* d_ws, size_t ws_size,
                              hipStream_t stream) {
    const float* images = (const float*)d_in[0];
    float* out = (float*)d_out;

    long long n = (long long)out_size;   // 67,108,864 floats
    long long n4 = n / 4;                // 16,777,216 x 16B

    // Guideline 11 (memory-bound): cap grid at full occupancy, grid-stride rest.
    // 2048 blocks x 256 = 8 blocks/CU = 32 waves/CU; 32 f32x4 per thread.
    int block = 256;
    long long want = (n4 + block - 1) / block;
    int grid = (int)(want < 2048 ? want : 2048);

    copy_f4_nt<<<grid, block, 0, stream>>>((const f32x4*)images, (f32x4*)out, n4);
}

// Round 3
// 421.829 us; speedup vs baseline: 1.0592x; 1.0592x over previous
//
#include <hip/hip_runtime.h>

// Reference = patchify ∘ depatchify = identity. Pure D2D copy.
// 64*1*1024*1024 floats = 256 MiB in + 256 MiB out = 512 MiB structural floor.
//
// ROUND-2 POST-MORTEM: nontemporal hints + 2048-block capped grid regressed
// the copy 90 -> 117 us (4.6 TB/s vs 6.0). The L3 is memory-side; nt
// write-around buys nothing and costs throughput. REVERTED to the round-0
// configuration (m13-style float4 grid-stride, 32768 blocks), which runs the
// copy at ~90 us ≈ 94% of the fill-measured 6.5 TB/s ceiling. Reported dur_us
// additionally contains ~330 us of harness poison-fills (2 x 1 GiB @ ~165 us).

__global__ __launch_bounds__(256) void copy_f4(const float4* __restrict__ src,
                                               float4* __restrict__ dst,
                                               long long n4) {
    long long i = (long long)blockIdx.x * blockDim.x + threadIdx.x;
    long long stride = (long long)gridDim.x * blockDim.x;
    for (; i < n4; i += stride) {
        dst[i] = src[i];
    }
}

extern "C" void kernel_launch(void* const* d_in, const int* in_sizes, int n_in,
                              void* d_out, int out_size, void* d_ws, size_t ws_size,
                              hipStream_t stream) {
    const float* images = (const float*)d_in[0];
    float* out = (float*)d_out;

    long long n = (long long)out_size;          // 67,108,864 floats
    long long n4 = n / 4;                        // 16,777,216 float4

    int block = 256;
    long long want = (n4 + block - 1) / block;
    int grid = (int)(want > 32768 ? 32768 : want);

    copy_f4<<<grid, block, 0, stream>>>((const float4*)images, (float4*)out, n4);
}